// Round 4
// baseline (26.638 us; speedup 1.0000x reference)
//
#include <hip/hip_runtime.h>
#include <hip/hip_bf16.h>

// Problem: B=8, L=4096, H=1024, K=512
// out[b,s,t] = col[b,s] = dot(seq[b, src_pos[b][s], :], w[:H])
//                       + dot(seq[b, tgt_pos[b][s], :], w[H:]) + bias
// src_pos/tgt_pos = ordered True positions of the masks (exactly K per row).
// Single fused kernel: one 64-lane wave per (b,s); the wave recomputes the
// s-th set-bit position of both mask rows itself (mask rows are L1-hot,
// shared by 512 waves), then does the dual dot + 2KB broadcast write.

#define L_DIM 4096
#define H_DIM 1024
#define K_DIM 512
#define B_DIM 8

typedef float f32x4 __attribute__((ext_vector_type(4)));

// position of the n-th (0-based) set bit of m (n < popcount(m))
__device__ __forceinline__ int nth_set(unsigned long long m, int n) {
    int pos = 0, c;
    c = __popcll(m & 0xFFFFFFFFull); if (n >= c) { n -= c; pos += 32; m >>= 32; }
    c = __popcll(m & 0xFFFFull);     if (n >= c) { n -= c; pos += 16; m >>= 16; }
    c = __popcll(m & 0xFFull);       if (n >= c) { n -= c; pos += 8;  m >>= 8;  }
    c = __popcll(m & 0xFull);        if (n >= c) { n -= c; pos += 4;  m >>= 4;  }
    c = __popcll(m & 0x3ull);        if (n >= c) { n -= c; pos += 2;  m >>= 2;  }
    c = (int)(m & 1ull);             if (n >= c) { pos += 1; }
    return pos;
}

__global__ __launch_bounds__(256) void fused_kernel(
    const float* __restrict__ seq,
    const void* __restrict__ smask, const void* __restrict__ tmask,
    const float* __restrict__ weight, const float* __restrict__ bias,
    float* __restrict__ out)
{
    const int wave = (blockIdx.x * 256 + threadIdx.x) >> 6;  // 0..B*K-1
    const int lane = threadIdx.x & 63;
    const int b = wave >> 9;            // / K_DIM
    const int s = wave & (K_DIM - 1);

    // ---- locate s-th set bit in src and tgt mask rows ----
    int pos[2];
#pragma unroll
    for (int mi = 0; mi < 2; ++mi) {
        const unsigned char* mp = (const unsigned char*)(mi ? tmask : smask);
        // byte-mode probe: lane covers bytes [lane*64, lane*64+64)
        unsigned long long m = 0ull;
        {
            const uint4* pb = (const uint4*)(mp + (size_t)b * L_DIM);
#pragma unroll
            for (int j = 0; j < 4; ++j) {
                uint4 u = pb[lane * 4 + j];
                const unsigned vals[4] = {u.x, u.y, u.z, u.w};
#pragma unroll
                for (int k = 0; k < 4; ++k) {
                    const unsigned v = vals[k];
                    const int base = j * 16 + k * 4;
                    if (v & 0x000000FFu) m |= 1ull << (base + 0);
                    if (v & 0x0000FF00u) m |= 1ull << (base + 1);
                    if (v & 0x00FF0000u) m |= 1ull << (base + 2);
                    if (v & 0xFF000000u) m |= 1ull << (base + 3);
                }
            }
        }
        int cnt = __popcll(m);
        int x = cnt;                     // inclusive prefix over lanes
#pragma unroll
        for (int off = 1; off < 64; off <<= 1) {
            int y = __shfl_up(x, off, 64);
            if (lane >= off) x += y;
        }
        if (__shfl(x, 63, 64) != K_DIM) {
            // int32 mode: lane covers ints [lane*64, lane*64+64)
            m = 0ull;
            const uint4* pi = (const uint4*)((const unsigned*)mp + (size_t)b * L_DIM);
#pragma unroll
            for (int j = 0; j < 16; ++j) {
                uint4 u = pi[lane * 16 + j];
                const int base = j * 4;
                if (u.x) m |= 1ull << (base + 0);
                if (u.y) m |= 1ull << (base + 1);
                if (u.z) m |= 1ull << (base + 2);
                if (u.w) m |= 1ull << (base + 3);
            }
            cnt = __popcll(m);
            x = cnt;
#pragma unroll
            for (int off = 1; off < 64; off <<= 1) {
                int y = __shfl_up(x, off, 64);
                if (lane >= off) x += y;
            }
        }
        const int exc = x - cnt;
        const bool own = (s >= exc) & (s < x);
        const unsigned long long sel = __ballot(own);
        const int l = (int)__builtin_ctzll(sel);
        const int p = own ? (lane * 64 + nth_set(m, s - exc)) : 0;
        pos[mi] = __shfl(p, l, 64);
    }

    // ---- dual dot product ----
    const float4* __restrict__ srow = (const float4*)(seq + ((size_t)b * L_DIM + pos[0]) * H_DIM);
    const float4* __restrict__ trow = (const float4*)(seq + ((size_t)b * L_DIM + pos[1]) * H_DIM);
    const float4* __restrict__ w1 = (const float4*)(weight);          // 256 float4
    const float4* __restrict__ w2 = (const float4*)(weight + H_DIM);

    float acc0 = 0.f, acc1 = 0.f;
#pragma unroll
    for (int j = 0; j < 4; ++j) {
        const int i = lane + 64 * j;
        float4 a = srow[i], wa = w1[i];
        float4 c = trow[i], wc = w2[i];
        acc0 += a.x * wa.x + a.y * wa.y + a.z * wa.z + a.w * wa.w;
        acc1 += c.x * wc.x + c.y * wc.y + c.z * wc.z + c.w * wc.w;
    }
    float acc = acc0 + acc1;
#pragma unroll
    for (int off = 32; off; off >>= 1) acc += __shfl_xor(acc, off, 64);

    const float col = acc + bias[0];
    const f32x4 v = {col, col, col, col};
    f32x4* orow = (f32x4*)(out + (size_t)wave * K_DIM);
    __builtin_nontemporal_store(v, &orow[lane]);
    __builtin_nontemporal_store(v, &orow[lane + 64]);
}

extern "C" void kernel_launch(void* const* d_in, const int* in_sizes, int n_in,
                              void* d_out, int out_size, void* d_ws, size_t ws_size,
                              hipStream_t stream) {
    const float* seq    = (const float*)d_in[0];
    const void*  smask  = d_in[1];
    const void*  tmask  = d_in[2];
    const float* weight = (const float*)d_in[3];
    const float* bias   = (const float*)d_in[4];
    float* out = (float*)d_out;
    (void)d_ws; (void)ws_size;

    fused_kernel<<<(B_DIM * K_DIM) / 4, 256, 0, stream>>>(seq, smask, tmask, weight, bias, out);
}

// Round 5
// 13.495 us; speedup vs baseline: 1.9739x; 1.9739x over previous
//
#include <hip/hip_runtime.h>
#include <hip/hip_bf16.h>

// Problem: B=8, L=4096, H=1024, K=512
// out[b,s,t] = col[b,s] = dot(seq[b, src_pos[b][s], :], w[:H])
//                       + dot(seq[b, tgt_pos[b][s], :], w[H:]) + bias
// Single dispatch: 1024 blocks x 256 threads. Each block = one (b, group of 4 s).
// The block cooperatively derives the 8 needed mask positions (block-amortized
// scan, ~600 cyc), then its 4 waves do the dual dot + 2KB broadcast write each.

#define L_DIM 4096
#define H_DIM 1024
#define K_DIM 512
#define B_DIM 8
#define PACKED_K (K_DIM | (K_DIM << 16))

typedef float f32x4 __attribute__((ext_vector_type(4)));

// 4 bytes (any-nonzero) -> 4-bit movemask, robust to 0/1 or 0/255 encodings
__device__ __forceinline__ unsigned nib4(unsigned w) {
    unsigned x = w | (w >> 4); x |= x >> 2; x |= x >> 1; x &= 0x01010101u;
    return ((x * 0x01020408u) >> 24) & 0xFu;
}
__device__ __forceinline__ unsigned mask16b(uint4 u) {
    return nib4(u.x) | (nib4(u.y) << 4) | (nib4(u.z) << 8) | (nib4(u.w) << 12);
}
// position of n-th (0-based) set bit of 16-bit m
__device__ __forceinline__ int nth16(unsigned m, int n) {
    int pos = 0, c;
    c = __popc(m & 0xFFu); if (n >= c) { n -= c; pos += 8; m >>= 8; }
    c = __popc(m & 0xFu);  if (n >= c) { n -= c; pos += 4; m >>= 4; }
    c = __popc(m & 0x3u);  if (n >= c) { n -= c; pos += 2; m >>= 2; }
    c = (int)(m & 1u);     if (n >= c) { pos += 1; }
    return pos;
}

__global__ __launch_bounds__(256) void fused_kernel(
    const float* __restrict__ seq,
    const void* __restrict__ smask, const void* __restrict__ tmask,
    const float* __restrict__ weight, const float* __restrict__ bias,
    float* __restrict__ out)
{
    const int tid  = threadIdx.x;      // 0..255
    const int wid  = tid >> 6;         // wave in block, 0..3
    const int lane = tid & 63;
    const int bb   = blockIdx.x;       // 0..1023
    const int b    = bb >> 7;          // batch
    const int sg   = (bb & 127) << 2;  // base s of this block's 4 ranks

    __shared__ int wtot[4];
    __shared__ int posLds[8];          // [0..3]=src pos, [4..7]=tgt pos

    // ---- cooperative probe: thread covers bytes [tid*16, tid*16+16) ----
    const uint4* sb = (const uint4*)((const unsigned char*)smask + (size_t)b * L_DIM);
    const uint4* tb = (const uint4*)((const unsigned char*)tmask + (size_t)b * L_DIM);
    unsigned mS = mask16b(sb[tid]);
    unsigned mT = mask16b(tb[tid]);
    int packed = __popc(mS) | (__popc(mT) << 16);

    int x = packed;                     // wave-inclusive scan (packed both masks)
#pragma unroll
    for (int off = 1; off < 64; off <<= 1) {
        int y = __shfl_up(x, off, 64);
        if (lane >= off) x += y;
    }
    if (lane == 63) wtot[wid] = x;
    __syncthreads();
    int off_ = 0, tot = 0;
#pragma unroll
    for (int w = 0; w < 4; ++w) { int v = wtot[w]; tot += v; if (w < wid) off_ += v; }
    x += off_;

    if (tot != PACKED_K) {              // block-uniform: masks are int32, redo
        __syncthreads();                // protect wtot before rewrite
        const uint4* si = (const uint4*)((const unsigned*)smask + (size_t)b * L_DIM) + tid * 4;
        const uint4* ti = (const uint4*)((const unsigned*)tmask + (size_t)b * L_DIM) + tid * 4;
        mS = 0u; mT = 0u;
#pragma unroll
        for (int j = 0; j < 4; ++j) {
            uint4 u = si[j], v = ti[j];
            const int base = j * 4;
            mS |= (((u.x != 0) ? 1u : 0u) << base) | (((u.y != 0) ? 1u : 0u) << (base + 1))
                | (((u.z != 0) ? 1u : 0u) << (base + 2)) | (((u.w != 0) ? 1u : 0u) << (base + 3));
            mT |= (((v.x != 0) ? 1u : 0u) << base) | (((v.y != 0) ? 1u : 0u) << (base + 1))
                | (((v.z != 0) ? 1u : 0u) << (base + 2)) | (((v.w != 0) ? 1u : 0u) << (base + 3));
        }
        packed = __popc(mS) | (__popc(mT) << 16);
        x = packed;
#pragma unroll
        for (int off = 1; off < 64; off <<= 1) {
            int y = __shfl_up(x, off, 64);
            if (lane >= off) x += y;
        }
        if (lane == 63) wtot[wid] = x;
        __syncthreads();
        off_ = 0;
#pragma unroll
        for (int w = 0; w < 4; ++w) { int v = wtot[w]; if (w < wid) off_ += v; }
        x += off_;
    }

    const int exc  = x - packed;        // exclusive prefix, packed
    const int excS = exc & 0xffff, excT = exc >> 16;   // fields never carry (<=512)
    const int cntS = __popc(mS), cntT = __popc(mT);
#pragma unroll
    for (int j = 0; j < 4; ++j) {
        const int s = sg + j;
        if (s >= excS && s < excS + cntS) posLds[j]     = tid * 16 + nth16(mS, s - excS);
        if (s >= excT && s < excT + cntT) posLds[4 + j] = tid * 16 + nth16(mT, s - excT);
    }
    __syncthreads();

    // ---- per-wave dual dot + broadcast write ----
    const int ps = posLds[wid];         // LDS broadcast reads (no conflict)
    const int pt = posLds[4 + wid];

    const float4* __restrict__ srow = (const float4*)(seq + ((size_t)b * L_DIM + ps) * H_DIM);
    const float4* __restrict__ trow = (const float4*)(seq + ((size_t)b * L_DIM + pt) * H_DIM);
    const float4* __restrict__ w1 = (const float4*)(weight);            // 256 float4
    const float4* __restrict__ w2 = (const float4*)(weight + H_DIM);

    float acc0 = 0.f, acc1 = 0.f;
#pragma unroll
    for (int j = 0; j < 4; ++j) {
        const int i = lane + 64 * j;
        float4 a = srow[i], wa = w1[i];
        float4 c = trow[i], wc = w2[i];
        acc0 += a.x * wa.x + a.y * wa.y + a.z * wa.z + a.w * wa.w;
        acc1 += c.x * wc.x + c.y * wc.y + c.z * wc.z + c.w * wc.w;
    }
    float acc = acc0 + acc1;
#pragma unroll
    for (int off = 32; off; off >>= 1) acc += __shfl_xor(acc, off, 64);

    const float col = acc + bias[0];
    const f32x4 v = {col, col, col, col};
    f32x4* orow = (f32x4*)(out + ((size_t)(b * K_DIM + sg + wid)) * K_DIM);
    __builtin_nontemporal_store(v, &orow[lane]);
    __builtin_nontemporal_store(v, &orow[lane + 64]);
}

extern "C" void kernel_launch(void* const* d_in, const int* in_sizes, int n_in,
                              void* d_out, int out_size, void* d_ws, size_t ws_size,
                              hipStream_t stream) {
    const float* seq    = (const float*)d_in[0];
    const void*  smask  = d_in[1];
    const void*  tmask  = d_in[2];
    const float* weight = (const float*)d_in[3];
    const float* bias   = (const float*)d_in[4];
    float* out = (float*)d_out;
    (void)d_ws; (void)ws_size;

    fused_kernel<<<1024, 256, 0, stream>>>(seq, smask, tmask, weight, bias, out);
}